// Round 3
// baseline (74.784 us; speedup 1.0000x reference)
//
#include <hip/hip_runtime.h>
#include <hip/hip_bf16.h>
#include <cmath>

// GraphAttention: out = elu((softmax(mask_diag(lrelu(si+sj'))) + I) @ h), h = x@W^T + b
// B=8 N=2048 IN=256 H=128, ALPHA=0.2. adj_identity is broadcast eye(N).
//
// Sorted-prefix algorithm (replaces O(N^2 H) flash matmul):
//   w_ij = (sj_j > -si_i) ? e1_i*f1_j : e2_i*f2_j,  f1=e^{sj}, f2=e^{a*sj},
//   e1=e^{si-m}, e2=e^{a*si-m}.  Sort j by sj desc -> branch-1 set is a prefix:
//   (W@h)_i = e1_i*S1[k_i] + e2_i*S2R[k_i],  Z_i = e1_i*FF1[k_i] + e2_i*FF2R[k_i]
//   with S1/S2R prefix/suffix sums of f1*h / f2*h in sorted order and
//   k_i = #{j: sj_j > -si_i} (plain count). Diagonal subtracted in epilogue.
//   m_i cancels exactly (scales num and den identically) -> only overflow guard.

#define ALPHA 0.2f
#define NB 8
#define NN 2048
#define NIN 256
#define NH 128

typedef __attribute__((ext_vector_type(8))) short short8;
typedef __attribute__((ext_vector_type(4))) float f32x4;

__device__ __forceinline__ unsigned short f2bf(float f) {
    unsigned int u = __float_as_uint(f);
    u += 0x7fffu + ((u >> 16) & 1u);   // round-to-nearest-even
    return (unsigned short)(u >> 16);
}

// ---------------------------------------------------------------------------
// K1: h = x @ W^T + b  (bf16 MFMA, fp32 accum). Writes h_f32 [16384][128],
// si/sj [16384]. Block: 256 thr (4 waves), 64 rows. Grid 256.
// ---------------------------------------------------------------------------
__global__ __launch_bounds__(256) void k1_h(
    const float* __restrict__ x, const float* __restrict__ Wm,
    const float* __restrict__ bias, const float* __restrict__ av,
    float* __restrict__ hout, float* __restrict__ si, float* __restrict__ sj)
{
    __shared__ __align__(16) unsigned short xls[64 * 264];   // [64 rows][256+8 pad] bf16
    __shared__ __align__(16) unsigned short Wls[128 * 264];  // [128 ch ][256+8 pad] bf16
    __shared__ float a1l[128], a2l[128], bl[128];

    const int t = threadIdx.x;
    const int r0 = blockIdx.x * 64;

    for (int p = 0; p < 16; ++p) {
        int idx = p * 256 + t;
        int row = idx >> 6, kq = idx & 63;
        f32x4 v = *(const f32x4*)(x + (size_t)(r0 + row) * NIN + kq * 4);
        unsigned int lo = (unsigned)f2bf(v[0]) | ((unsigned)f2bf(v[1]) << 16);
        unsigned int hi = (unsigned)f2bf(v[2]) | ((unsigned)f2bf(v[3]) << 16);
        *(uint2*)(&xls[row * 264 + kq * 4]) = make_uint2(lo, hi);
    }
    for (int p = 0; p < 32; ++p) {
        int idx = p * 256 + t;
        int row = idx >> 6, kq = idx & 63;
        f32x4 v = *(const f32x4*)(Wm + (size_t)row * NIN + kq * 4);
        unsigned int lo = (unsigned)f2bf(v[0]) | ((unsigned)f2bf(v[1]) << 16);
        unsigned int hi = (unsigned)f2bf(v[2]) | ((unsigned)f2bf(v[3]) << 16);
        *(uint2*)(&Wls[row * 264 + kq * 4]) = make_uint2(lo, hi);
    }
    if (t < 128) { a1l[t] = av[t]; a2l[t] = av[128 + t]; bl[t] = bias[t]; }
    __syncthreads();

    const int w = t >> 6, l = t & 63, la = l & 15, g = l >> 4;

    f32x4 acc[8];
#pragma unroll
    for (int n = 0; n < 8; ++n) acc[n] = (f32x4){0.f, 0.f, 0.f, 0.f};

#pragma unroll
    for (int ks = 0; ks < 8; ++ks) {
        short8 af = *(const short8*)(&xls[(w * 16 + la) * 264 + ks * 32 + g * 8]);
#pragma unroll
        for (int n = 0; n < 8; ++n) {
            short8 bfr = *(const short8*)(&Wls[(n * 16 + la) * 264 + ks * 32 + g * 8]);
            acc[n] = __builtin_amdgcn_mfma_f32_16x16x32_bf16(af, bfr, acc[n], 0, 0, 0);
        }
    }

    float s1[4] = {0.f, 0.f, 0.f, 0.f}, s2[4] = {0.f, 0.f, 0.f, 0.f};
#pragma unroll
    for (int n = 0; n < 8; ++n) {
        int col = n * 16 + la;
#pragma unroll
        for (int r = 0; r < 4; ++r) {
            float v = acc[n][r] + bl[col];
            int row = w * 16 + g * 4 + r;
            hout[(size_t)(r0 + row) * NH + col] = v;
            s1[r] += v * a1l[col];
            s2[r] += v * a2l[col];
        }
    }
#pragma unroll
    for (int r = 0; r < 4; ++r) {
#pragma unroll
        for (int m = 1; m < 16; m <<= 1) {
            s1[r] += __shfl_xor(s1[r], m, 64);
            s2[r] += __shfl_xor(s2[r], m, 64);
        }
    }
    if (la == 0) {
#pragma unroll
        for (int r = 0; r < 4; ++r) {
            int row = w * 16 + g * 4 + r;
            si[r0 + row] = s1[r];
            sj[r0 + row] = s2[r];
        }
    }
}

// ---------------------------------------------------------------------------
// K2: rank-by-count (desc by sj, tie-break by index), k_i count, stats.
// Grid 8 batches x 16 blocks, block 256 (128 j's per block, 2 scan-halves).
// ---------------------------------------------------------------------------
__global__ __launch_bounds__(256) void k2_rank(
    const float* __restrict__ si, const float* __restrict__ sj,
    int* __restrict__ perm, float* __restrict__ f1s, float* __restrict__ f2s,
    int* __restrict__ kk, float* __restrict__ e1g, float* __restrict__ e2g,
    float* __restrict__ ownw)
{
    __shared__ __align__(16) float sjl[NN];
    __shared__ float red1[4], red2[4];
    __shared__ int lcnt[2][128][3];

    const int t = threadIdx.x;
    const int b = blockIdx.x >> 4;
    const int j0 = (blockIdx.x & 15) * 128;
    const float* sjb = sj + b * NN;

    for (int p = 0; p < 2; ++p) {
        int idx = p * 256 + t;
        ((f32x4*)sjl)[idx] = ((const f32x4*)sjb)[idx];
    }
    __syncthreads();

    // global max1/max2 of sj (overflow-guard m only; m cancels exactly)
    float m1 = -3.4e38f, m2 = -3.4e38f;
    for (int p = 0; p < 8; ++p) {
        float v = sjl[p * 256 + t];
        if (v > m1) { m2 = m1; m1 = v; } else if (v > m2) m2 = v;
    }
    for (int m = 1; m < 64; m <<= 1) {
        float o1 = __shfl_xor(m1, m, 64), o2 = __shfl_xor(m2, m, 64);
        float n1 = fmaxf(m1, o1);
        float n2 = fmaxf(fminf(m1, o1), fmaxf(m2, o2));
        m1 = n1; m2 = n2;
    }
    if ((t & 63) == 0) { red1[t >> 6] = m1; red2[t >> 6] = m2; }
    __syncthreads();
    {
        float a1 = red1[0], a2 = red2[0];
#pragma unroll
        for (int wv = 1; wv < 4; ++wv) {
            float b1 = red1[wv], b2 = red2[wv];
            float n1 = fmaxf(a1, b1), n2 = fmaxf(fminf(a1, b1), fmaxf(a2, b2));
            a1 = n1; a2 = n2;
        }
        m1 = a1; m2 = a2;
    }

    const int lane = t & 127, half = t >> 7;
    const int jj = j0 + lane;
    const float val = sjl[jj];             // sj of index jj
    const float svi = si[b * NN + jj];     // si of row i = jj
    const float thr = -svi;

    int cgt = 0, ceq = 0, kc = 0;
    const int base = half * 1024;
    for (int q = 0; q < 256; ++q) {
        f32x4 v = ((const f32x4*)(sjl + base))[q];
        int idx = base + q * 4;
#pragma unroll
        for (int u = 0; u < 4; ++u) {
            float x = v[u];
            cgt += (x > val) ? 1 : 0;
            ceq += (x == val && (idx + u) < jj) ? 1 : 0;
            kc  += (x > thr) ? 1 : 0;
        }
    }
    lcnt[half][lane][0] = cgt; lcnt[half][lane][1] = ceq; lcnt[half][lane][2] = kc;
    __syncthreads();
    if (half == 0) {
        int rank = cgt + ceq + lcnt[1][lane][0] + lcnt[1][lane][1];
        int k    = kc + lcnt[1][lane][2];
        int gj = b * NN + jj;
        perm[b * NN + rank] = jj;
        f1s[b * NN + rank] = expf(val);
        f2s[b * NN + rank] = expf(ALPHA * val);
        kk[gj] = k;
        float M = (val == m1) ? m2 : m1;       // max_{k!=i} sj_k (dup-max safe)
        float sm = svi + M;
        float m = sm > 0.f ? sm : ALPHA * sm;  // m_i = lrelu(si+M) — guard only
        e1g[gj] = expf(svi - m);
        e2g[gj] = expf(ALPHA * svi - m);
        float sd = svi + val;
        float lr = sd > 0.f ? sd : ALPHA * sd;
        ownw[gj] = expf(lr - m);               // w_ii, subtracted in K4
    }
}

// ---------------------------------------------------------------------------
// K3a: per-chunk (64 sorted rows) partial sums of f1*h and f2*h.
// Grid 8x32 = 256 blocks, block 256 (128 cols x 2 arrays).
// ---------------------------------------------------------------------------
__global__ __launch_bounds__(256) void k3_chunksum(
    const float* __restrict__ h, const int* __restrict__ perm,
    const float* __restrict__ f1s, const float* __restrict__ f2s,
    float* __restrict__ cS1, float* __restrict__ cS2,
    float* __restrict__ cF1, float* __restrict__ cF2)
{
    __shared__ int pl[64];
    __shared__ float f1l[64], f2l[64];
    const int t = threadIdx.x;
    const int b = blockIdx.x >> 5, ch = blockIdx.x & 31;
    const int r0 = ch * 64;
    if (t < 64) {
        pl[t]  = perm[b * NN + r0 + t];
        f1l[t] = f1s[b * NN + r0 + t];
        f2l[t] = f2s[b * NN + r0 + t];
    }
    __syncthreads();
    const int c = t & 127, which = t >> 7;
    const float* fl = which ? f2l : f1l;
    float acc = 0.f;
#pragma unroll 4
    for (int r = 0; r < 64; ++r) {
        acc += fl[r] * h[(size_t)(b * NN + pl[r]) * NH + c];
    }
    (which ? cS2 : cS1)[(b * 32 + ch) * NH + c] = acc;
    if (t == 0)   { float s = 0.f; for (int r = 0; r < 64; ++r) s += f1l[r]; cF1[b * 32 + ch] = s; }
    if (t == 128) { float s = 0.f; for (int r = 0; r < 64; ++r) s += f2l[r]; cF2[b * 32 + ch] = s; }
}

// ---------------------------------------------------------------------------
// K3c: full prefix S1 / suffix S2R arrays [B][2049][128] + scalar FF1/FF2R.
// Grid 8x32, block 256. Offsets from chunk sums; in-chunk 64-step scan.
// ---------------------------------------------------------------------------
__global__ __launch_bounds__(256) void k3_scan(
    const float* __restrict__ h, const int* __restrict__ perm,
    const float* __restrict__ f1s, const float* __restrict__ f2s,
    const float* __restrict__ cS1, const float* __restrict__ cS2,
    const float* __restrict__ cF1, const float* __restrict__ cF2,
    float* __restrict__ S1, float* __restrict__ S2R,
    float* __restrict__ FF1, float* __restrict__ FF2R)
{
    __shared__ __align__(16) float hl[64][128];
    __shared__ int pl[64];
    __shared__ float f1l[64], f2l[64];
    const int t = threadIdx.x;
    const int b = blockIdx.x >> 5, ch = blockIdx.x & 31;
    const int r0 = ch * 64;
    if (t < 64) {
        pl[t]  = perm[b * NN + r0 + t];
        f1l[t] = f1s[b * NN + r0 + t];
        f2l[t] = f2s[b * NN + r0 + t];
    }
    __syncthreads();
    {
        int lane = t & 31, rr = t >> 5;
#pragma unroll
        for (int k8 = 0; k8 < 8; ++k8) {
            int r = rr + k8 * 8;
            f32x4 v = *(const f32x4*)(h + (size_t)(b * NN + pl[r]) * NH + lane * 4);
            *(f32x4*)(&hl[r][lane * 4]) = v;
        }
    }
    const int c = t & 127, which = t >> 7;
    float off = 0.f;
    if (which == 0) {
        for (int cc = 0; cc < ch; ++cc) off += cS1[(b * 32 + cc) * NH + c];
    } else {
        for (int cc = ch + 1; cc < 32; ++cc) off += cS2[(b * 32 + cc) * NH + c];
    }
    __syncthreads();
    const size_t sbase = ((size_t)b * 2049 + r0) * NH + c;
    if (which == 0) {
        float acc = off;
        for (int r = 0; r < 64; ++r) {
            S1[sbase + (size_t)r * NH] = acc;
            acc += f1l[r] * hl[r][c];
        }
        if (ch == 31) S1[((size_t)b * 2049 + 2048) * NH + c] = acc;
    } else {
        float acc = off;
        for (int r = 63; r >= 0; --r) {
            acc += f2l[r] * hl[r][c];
            S2R[sbase + (size_t)r * NH] = acc;
        }
        if (ch == 31) S2R[((size_t)b * 2049 + 2048) * NH + c] = 0.f;
    }
    if (t == 0) {
        float o = 0.f;
        for (int cc = 0; cc < ch; ++cc) o += cF1[b * 32 + cc];
        for (int r = 0; r < 64; ++r) { FF1[b * 2049 + r0 + r] = o; o += f1l[r]; }
        if (ch == 31) FF1[b * 2049 + 2048] = o;
    }
    if (t == 128) {
        float o = 0.f;
        for (int cc = ch + 1; cc < 32; ++cc) o += cF2[b * 32 + cc];
        for (int r = 63; r >= 0; --r) { o += f2l[r]; FF2R[b * 2049 + r0 + r] = o; }
        if (ch == 31) FF2R[b * 2049 + 2048] = 0.f;
    }
}

// ---------------------------------------------------------------------------
// K4: per-row gather + epilogue. Grid 2048, block 256 (8 rows x 32 lanes x4).
// ---------------------------------------------------------------------------
__global__ __launch_bounds__(256) void k4_out(
    const float* __restrict__ h, const int* __restrict__ kk,
    const float* __restrict__ e1g, const float* __restrict__ e2g,
    const float* __restrict__ owng,
    const float* __restrict__ S1, const float* __restrict__ S2R,
    const float* __restrict__ FF1, const float* __restrict__ FF2R,
    float* __restrict__ out)
{
    const int t = threadIdx.x;
    const int lane = t & 31, rloc = t >> 5;
    const int row = blockIdx.x * 8 + rloc;
    const int b = row >> 11;
    float e1v = 0.f, e2v = 0.f, ow = 0.f, den = 1.f; int k = 0;
    if (lane == 0) {
        k = kk[row];
        e1v = e1g[row]; e2v = e2g[row]; ow = owng[row];
        den = e1v * FF1[b * 2049 + k] + e2v * FF2R[b * 2049 + k] - ow;
    }
    k   = __shfl(k, 0, 32);
    e1v = __shfl(e1v, 0, 32);
    e2v = __shfl(e2v, 0, 32);
    ow  = __shfl(ow, 0, 32);
    den = __shfl(den, 0, 32);
    const float rden = 1.f / den;
    const size_t srow = ((size_t)b * 2049 + k) * NH + lane * 4;
    f32x4 s1 = *(const f32x4*)(S1 + srow);
    f32x4 s2 = *(const f32x4*)(S2R + srow);
    f32x4 hv = *(const f32x4*)(h + (size_t)row * NH + lane * 4);
    f32x4 o;
#pragma unroll
    for (int u = 0; u < 4; ++u) {
        float num = e1v * s1[u] + e2v * s2[u] - ow * hv[u];
        float v = num * rden + hv[u];
        o[u] = v > 0.f ? v : expm1f(v);
    }
    *(f32x4*)(out + (size_t)row * NH + lane * 4) = o;
}

// ---------------------------------------------------------------------------
extern "C" void kernel_launch(void* const* d_in, const int* in_sizes, int n_in,
                              void* d_out, int out_size, void* d_ws, size_t ws_size,
                              hipStream_t stream)
{
    const float* x    = (const float*)d_in[0];
    // d_in[1] = adj_identity (broadcast eye(N)) — handled analytically, never read.
    const float* Wm   = (const float*)d_in[2];
    const float* bias = (const float*)d_in[3];
    const float* av   = (const float*)d_in[4];
    float* out = (float*)d_out;

    float* wsf = (float*)d_ws;
    float* h    = wsf;                  // 2,097,152
    float* si   = wsf + 2097152;        // 16384
    float* sj   = wsf + 2113536;
    float* e1   = wsf + 2129920;
    float* e2   = wsf + 2146304;
    float* own  = wsf + 2162688;
    float* f1s  = wsf + 2179072;
    float* f2s  = wsf + 2195456;
    int*   kk   = (int*)(wsf + 2211840);
    int*   perm = (int*)(wsf + 2228224);
    float* cS1  = wsf + 2244608;        // 8*32*128 = 32768
    float* cS2  = wsf + 2277376;
    float* cF1  = wsf + 2310144;        // 256
    float* cF2  = wsf + 2310400;        // 256
    float* FF1  = wsf + 2310656;        // 16392 (pad 16640)
    float* FF2R = wsf + 2327296;
    float* S1   = wsf + 2343936;        // 8*2049*128 = 2,098,176
    float* S2R  = wsf + 4442112;

    hipLaunchKernelGGL(k1_h,        dim3(256),  dim3(256), 0, stream, x, Wm, bias, av, h, si, sj);
    hipLaunchKernelGGL(k2_rank,     dim3(128),  dim3(256), 0, stream, si, sj, perm, f1s, f2s, kk, e1, e2, own);
    hipLaunchKernelGGL(k3_chunksum, dim3(256),  dim3(256), 0, stream, h, perm, f1s, f2s, cS1, cS2, cF1, cF2);
    hipLaunchKernelGGL(k3_scan,     dim3(256),  dim3(256), 0, stream, h, perm, f1s, f2s, cS1, cS2, cF1, cF2, S1, S2R, FF1, FF2R);
    hipLaunchKernelGGL(k4_out,      dim3(2048), dim3(256), 0, stream, h, kk, e1, e2, own, S1, S2R, FF1, FF2R, out);
}

// Round 4
// 69.571 us; speedup vs baseline: 1.0749x; 1.0749x over previous
//
#include <hip/hip_runtime.h>
#include <hip/hip_bf16.h>
#include <cmath>

// GraphAttention: out = elu((softmax(mask_diag(lrelu(si+sj'))) + I) @ h), h = x@W^T + b
// B=8 N=2048 IN=256 H=128, ALPHA=0.2. adj_identity is broadcast eye(N).
//
// Sorted-prefix algorithm:
//   w_ij = (sj_j > -si_i) ? e1_i*f1_j : e2_i*f2_j,  f1=e^{sj}, f2=e^{a*sj}.
//   Sort j by sj desc -> branch-1 set is a prefix:
//   (W@h)_i = e1_i*S1[k_i] + e2_i*S2R[k_i],  Z_i = e1_i*FF1[k_i] + e2_i*FF2R[k_i]
//   with S1/S2R prefix/suffix sums of f1*h / f2*h in sorted order and
//   k_i = #{j: sj_j > -si_i}. Diagonal subtracted in the epilogue; m_i cancels.
//
// R4: halved serial chains (32-row half-chunks), 512-thread rank kernel,
// shuffle-reduced scalar sums — attacking exposed latency, not BW.

#define ALPHA 0.2f
#define NB 8
#define NN 2048
#define NIN 256
#define NH 128

typedef __attribute__((ext_vector_type(8))) short short8;
typedef __attribute__((ext_vector_type(4))) float f32x4;

__device__ __forceinline__ unsigned short f2bf(float f) {
    unsigned int u = __float_as_uint(f);
    u += 0x7fffu + ((u >> 16) & 1u);   // round-to-nearest-even
    return (unsigned short)(u >> 16);
}

// ---------------------------------------------------------------------------
// K1: h = x @ W^T + b  (bf16 MFMA, fp32 accum). Writes h_f32 [16384][128],
// si/sj [16384]. Block: 256 thr (4 waves), 64 rows. Grid 256.
// ---------------------------------------------------------------------------
__global__ __launch_bounds__(256) void k1_h(
    const float* __restrict__ x, const float* __restrict__ Wm,
    const float* __restrict__ bias, const float* __restrict__ av,
    float* __restrict__ hout, float* __restrict__ si, float* __restrict__ sj)
{
    __shared__ __align__(16) unsigned short xls[64 * 264];   // [64 rows][256+8 pad] bf16
    __shared__ __align__(16) unsigned short Wls[128 * 264];  // [128 ch ][256+8 pad] bf16
    __shared__ float a1l[128], a2l[128], bl[128];

    const int t = threadIdx.x;
    const int r0 = blockIdx.x * 64;

    for (int p = 0; p < 16; ++p) {
        int idx = p * 256 + t;
        int row = idx >> 6, kq = idx & 63;
        f32x4 v = *(const f32x4*)(x + (size_t)(r0 + row) * NIN + kq * 4);
        unsigned int lo = (unsigned)f2bf(v[0]) | ((unsigned)f2bf(v[1]) << 16);
        unsigned int hi = (unsigned)f2bf(v[2]) | ((unsigned)f2bf(v[3]) << 16);
        *(uint2*)(&xls[row * 264 + kq * 4]) = make_uint2(lo, hi);
    }
    for (int p = 0; p < 32; ++p) {
        int idx = p * 256 + t;
        int row = idx >> 6, kq = idx & 63;
        f32x4 v = *(const f32x4*)(Wm + (size_t)row * NIN + kq * 4);
        unsigned int lo = (unsigned)f2bf(v[0]) | ((unsigned)f2bf(v[1]) << 16);
        unsigned int hi = (unsigned)f2bf(v[2]) | ((unsigned)f2bf(v[3]) << 16);
        *(uint2*)(&Wls[row * 264 + kq * 4]) = make_uint2(lo, hi);
    }
    if (t < 128) { a1l[t] = av[t]; a2l[t] = av[128 + t]; bl[t] = bias[t]; }
    __syncthreads();

    const int w = t >> 6, l = t & 63, la = l & 15, g = l >> 4;

    f32x4 acc[8];
#pragma unroll
    for (int n = 0; n < 8; ++n) acc[n] = (f32x4){0.f, 0.f, 0.f, 0.f};

#pragma unroll
    for (int ks = 0; ks < 8; ++ks) {
        short8 af = *(const short8*)(&xls[(w * 16 + la) * 264 + ks * 32 + g * 8]);
#pragma unroll
        for (int n = 0; n < 8; ++n) {
            short8 bfr = *(const short8*)(&Wls[(n * 16 + la) * 264 + ks * 32 + g * 8]);
            acc[n] = __builtin_amdgcn_mfma_f32_16x16x32_bf16(af, bfr, acc[n], 0, 0, 0);
        }
    }

    float s1[4] = {0.f, 0.f, 0.f, 0.f}, s2[4] = {0.f, 0.f, 0.f, 0.f};
#pragma unroll
    for (int n = 0; n < 8; ++n) {
        int col = n * 16 + la;
#pragma unroll
        for (int r = 0; r < 4; ++r) {
            float v = acc[n][r] + bl[col];
            int row = w * 16 + g * 4 + r;
            hout[(size_t)(r0 + row) * NH + col] = v;
            s1[r] += v * a1l[col];
            s2[r] += v * a2l[col];
        }
    }
#pragma unroll
    for (int r = 0; r < 4; ++r) {
#pragma unroll
        for (int m = 1; m < 16; m <<= 1) {
            s1[r] += __shfl_xor(s1[r], m, 64);
            s2[r] += __shfl_xor(s2[r], m, 64);
        }
    }
    if (la == 0) {
#pragma unroll
        for (int r = 0; r < 4; ++r) {
            int row = w * 16 + g * 4 + r;
            si[r0 + row] = s1[r];
            sj[r0 + row] = s2[r];
        }
    }
}

// ---------------------------------------------------------------------------
// K2: rank-by-count (desc by sj, tie-break by index), k_i count, stats.
// Grid 8 batches x 16 blocks, block 512: 128 j's/block, 4-way scan split.
// ---------------------------------------------------------------------------
__global__ __launch_bounds__(512) void k2_rank(
    const float* __restrict__ si, const float* __restrict__ sj,
    int* __restrict__ perm, float* __restrict__ f1s, float* __restrict__ f2s,
    int* __restrict__ kk, float* __restrict__ e1g, float* __restrict__ e2g,
    float* __restrict__ ownw)
{
    __shared__ __align__(16) float sjl[NN];
    __shared__ float red1[8], red2[8];
    __shared__ int lcnt[4][128][3];

    const int t = threadIdx.x;
    const int b = blockIdx.x >> 4;
    const int j0 = (blockIdx.x & 15) * 128;
    const float* sjb = sj + b * NN;

    ((f32x4*)sjl)[t] = ((const f32x4*)sjb)[t];
    __syncthreads();

    // global max1/max2 of sj (overflow-guard m only; m cancels exactly)
    float m1 = -3.4e38f, m2 = -3.4e38f;
#pragma unroll
    for (int p = 0; p < 4; ++p) {
        float v = sjl[p * 512 + t];
        if (v > m1) { m2 = m1; m1 = v; } else if (v > m2) m2 = v;
    }
#pragma unroll
    for (int m = 1; m < 64; m <<= 1) {
        float o1 = __shfl_xor(m1, m, 64), o2 = __shfl_xor(m2, m, 64);
        float n1 = fmaxf(m1, o1);
        float n2 = fmaxf(fminf(m1, o1), fmaxf(m2, o2));
        m1 = n1; m2 = n2;
    }
    if ((t & 63) == 0) { red1[t >> 6] = m1; red2[t >> 6] = m2; }
    __syncthreads();
    {
        float a1 = red1[0], a2 = red2[0];
#pragma unroll
        for (int wv = 1; wv < 8; ++wv) {
            float b1 = red1[wv], b2 = red2[wv];
            float n1 = fmaxf(a1, b1), n2 = fmaxf(fminf(a1, b1), fmaxf(a2, b2));
            a1 = n1; a2 = n2;
        }
        m1 = a1; m2 = a2;
    }

    const int lane = t & 127, q = t >> 7;
    const int jj = j0 + lane;
    const float val = sjl[jj];             // sj of index jj
    const float svi = si[b * NN + jj];     // si of row i = jj
    const float thr = -svi;

    int cgt = 0, ceq = 0, kc = 0;
    const int base = q * 512;
    for (int p = 0; p < 128; ++p) {
        f32x4 v = ((const f32x4*)(sjl + base))[p];
        int idx = base + p * 4;
#pragma unroll
        for (int u = 0; u < 4; ++u) {
            float x = v[u];
            cgt += (x > val) ? 1 : 0;
            ceq += (x == val && (idx + u) < jj) ? 1 : 0;
            kc  += (x > thr) ? 1 : 0;
        }
    }
    lcnt[q][lane][0] = cgt; lcnt[q][lane][1] = ceq; lcnt[q][lane][2] = kc;
    __syncthreads();
    if (q == 0) {
        int rank = 0, k = 0;
#pragma unroll
        for (int qq = 0; qq < 4; ++qq) {
            rank += lcnt[qq][lane][0] + lcnt[qq][lane][1];
            k    += lcnt[qq][lane][2];
        }
        int gj = b * NN + jj;
        perm[b * NN + rank] = jj;
        f1s[b * NN + rank] = expf(val);
        f2s[b * NN + rank] = expf(ALPHA * val);
        kk[gj] = k;
        float M = (val == m1) ? m2 : m1;       // max_{k!=i} sj_k (dup-max safe)
        float sm = svi + M;
        float m = sm > 0.f ? sm : ALPHA * sm;  // m_i = lrelu(si+M) — guard only
        e1g[gj] = expf(svi - m);
        e2g[gj] = expf(ALPHA * svi - m);
        float sd = svi + val;
        float lr = sd > 0.f ? sd : ALPHA * sd;
        ownw[gj] = expf(lr - m);               // w_ii, subtracted in K4
    }
}

// ---------------------------------------------------------------------------
// K3a: per-half-chunk (32 sorted rows) partial sums of f1*h and f2*h.
// Grid 8x64 = 512 blocks, block 256 (128 cols x 2 arrays). 32-iter gather.
// ---------------------------------------------------------------------------
__global__ __launch_bounds__(256) void k3_chunksum(
    const float* __restrict__ h, const int* __restrict__ perm,
    const float* __restrict__ f1s, const float* __restrict__ f2s,
    float* __restrict__ cS1, float* __restrict__ cS2,
    float* __restrict__ cF1, float* __restrict__ cF2)
{
    __shared__ int pl[32];
    __shared__ float f1l[32], f2l[32];
    const int t = threadIdx.x;
    const int b = blockIdx.x >> 6, hc = blockIdx.x & 63;
    const int r0 = hc * 32;
    if (t < 32) {
        pl[t]  = perm[b * NN + r0 + t];
        f1l[t] = f1s[b * NN + r0 + t];
        f2l[t] = f2s[b * NN + r0 + t];
    }
    __syncthreads();
    const int c = t & 127, which = t >> 7;
    const float* fl = which ? f2l : f1l;
    float acc = 0.f;
#pragma unroll 8
    for (int r = 0; r < 32; ++r) {
        acc += fl[r] * h[(size_t)(b * NN + pl[r]) * NH + c];
    }
    (which ? cS2 : cS1)[(b * 64 + hc) * NH + c] = acc;
    // scalar f-sums via 32-lane shuffle reduce (waves 0 and 2, lanes 0-31)
    if (t < 32) {
        float s = f1l[t];
#pragma unroll
        for (int m = 1; m < 32; m <<= 1) s += __shfl_xor(s, m, 32);
        if (t == 0) cF1[b * 64 + hc] = s;
    } else if (t >= 128 && t < 160) {
        float s = f2l[t - 128];
#pragma unroll
        for (int m = 1; m < 32; m <<= 1) s += __shfl_xor(s, m, 32);
        if (t == 128) cF2[b * 64 + hc] = s;
    }
}

// ---------------------------------------------------------------------------
// K3c: full prefix S1 / suffix S2R arrays [B][2049][128] + scalar FF1/FF2R.
// Grid 8x64 = 512, block 256. Offsets from half-chunk sums; 32-step scan.
// ---------------------------------------------------------------------------
__global__ __launch_bounds__(256) void k3_scan(
    const float* __restrict__ h, const int* __restrict__ perm,
    const float* __restrict__ f1s, const float* __restrict__ f2s,
    const float* __restrict__ cS1, const float* __restrict__ cS2,
    const float* __restrict__ cF1, const float* __restrict__ cF2,
    float* __restrict__ S1, float* __restrict__ S2R,
    float* __restrict__ FF1, float* __restrict__ FF2R)
{
    __shared__ __align__(16) float hl[32][128];
    __shared__ int pl[32];
    __shared__ float f1l[32], f2l[32];
    const int t = threadIdx.x;
    const int b = blockIdx.x >> 6, hc = blockIdx.x & 63;
    const int r0 = hc * 32;
    if (t < 32) {
        pl[t]  = perm[b * NN + r0 + t];
        f1l[t] = f1s[b * NN + r0 + t];
        f2l[t] = f2s[b * NN + r0 + t];
    }
    __syncthreads();
    {
        int lane = t & 31, rr = t >> 5;
#pragma unroll
        for (int k4 = 0; k4 < 4; ++k4) {
            int r = rr + k4 * 8;
            f32x4 v = *(const f32x4*)(h + (size_t)(b * NN + pl[r]) * NH + lane * 4);
            *(f32x4*)(&hl[r][lane * 4]) = v;
        }
    }
    const int c = t & 127, which = t >> 7;
    float off = 0.f;
    if (which == 0) {
        for (int cc = 0; cc < hc; ++cc) off += cS1[(b * 64 + cc) * NH + c];
    } else {
        for (int cc = hc + 1; cc < 64; ++cc) off += cS2[(b * 64 + cc) * NH + c];
    }
    __syncthreads();
    const size_t sbase = ((size_t)b * 2049 + r0) * NH + c;
    if (which == 0) {
        float acc = off;
#pragma unroll 8
        for (int r = 0; r < 32; ++r) {
            S1[sbase + (size_t)r * NH] = acc;
            acc += f1l[r] * hl[r][c];
        }
        if (hc == 63) S1[((size_t)b * 2049 + 2048) * NH + c] = acc;
    } else {
        float acc = off;
#pragma unroll 8
        for (int r = 31; r >= 0; --r) {
            acc += f2l[r] * hl[r][c];
            S2R[sbase + (size_t)r * NH] = acc;
        }
        if (hc == 63) S2R[((size_t)b * 2049 + 2048) * NH + c] = 0.f;
    }
    if (t == 0) {
        float o = 0.f;
        for (int cc = 0; cc < hc; ++cc) o += cF1[b * 64 + cc];
        for (int r = 0; r < 32; ++r) { FF1[b * 2049 + r0 + r] = o; o += f1l[r]; }
        if (hc == 63) FF1[b * 2049 + 2048] = o;
    }
    if (t == 128) {
        float o = 0.f;
        for (int cc = hc + 1; cc < 64; ++cc) o += cF2[b * 64 + cc];
        for (int r = 31; r >= 0; --r) { o += f2l[r]; FF2R[b * 2049 + r0 + r] = o; }
        if (hc == 63) FF2R[b * 2049 + 2048] = 0.f;
    }
}

// ---------------------------------------------------------------------------
// K4: per-row gather + epilogue. Grid 2048, block 256 (8 rows x 32 lanes x4).
// ---------------------------------------------------------------------------
__global__ __launch_bounds__(256) void k4_out(
    const float* __restrict__ h, const int* __restrict__ kk,
    const float* __restrict__ e1g, const float* __restrict__ e2g,
    const float* __restrict__ owng,
    const float* __restrict__ S1, const float* __restrict__ S2R,
    const float* __restrict__ FF1, const float* __restrict__ FF2R,
    float* __restrict__ out)
{
    const int t = threadIdx.x;
    const int lane = t & 31, rloc = t >> 5;
    const int row = blockIdx.x * 8 + rloc;
    const int b = row >> 11;
    float e1v = 0.f, e2v = 0.f, ow = 0.f, den = 1.f; int k = 0;
    if (lane == 0) {
        k = kk[row];
        e1v = e1g[row]; e2v = e2g[row]; ow = owng[row];
        den = e1v * FF1[b * 2049 + k] + e2v * FF2R[b * 2049 + k] - ow;
    }
    k   = __shfl(k, 0, 32);
    e1v = __shfl(e1v, 0, 32);
    e2v = __shfl(e2v, 0, 32);
    ow  = __shfl(ow, 0, 32);
    den = __shfl(den, 0, 32);
    const float rden = 1.f / den;
    const size_t srow = ((size_t)b * 2049 + k) * NH + lane * 4;
    f32x4 s1 = *(const f32x4*)(S1 + srow);
    f32x4 s2 = *(const f32x4*)(S2R + srow);
    f32x4 hv = *(const f32x4*)(h + (size_t)row * NH + lane * 4);
    f32x4 o;
#pragma unroll
    for (int u = 0; u < 4; ++u) {
        float num = e1v * s1[u] + e2v * s2[u] - ow * hv[u];
        float v = num * rden + hv[u];
        o[u] = v > 0.f ? v : expm1f(v);
    }
    *(f32x4*)(out + (size_t)row * NH + lane * 4) = o;
}

// ---------------------------------------------------------------------------
extern "C" void kernel_launch(void* const* d_in, const int* in_sizes, int n_in,
                              void* d_out, int out_size, void* d_ws, size_t ws_size,
                              hipStream_t stream)
{
    const float* x    = (const float*)d_in[0];
    // d_in[1] = adj_identity (broadcast eye(N)) — handled analytically, never read.
    const float* Wm   = (const float*)d_in[2];
    const float* bias = (const float*)d_in[3];
    const float* av   = (const float*)d_in[4];
    float* out = (float*)d_out;

    float* wsf = (float*)d_ws;
    float* h    = wsf;                  // 2,097,152
    float* si   = wsf + 2097152;        // 16384
    float* sj   = wsf + 2113536;
    float* e1   = wsf + 2129920;
    float* e2   = wsf + 2146304;
    float* own  = wsf + 2162688;
    float* f1s  = wsf + 2179072;
    float* f2s  = wsf + 2195456;
    int*   kk   = (int*)(wsf + 2211840);
    int*   perm = (int*)(wsf + 2228224);
    float* cS1  = wsf + 2244608;        // 8*64*128 = 65536
    float* cS2  = wsf + 2310144;        // 65536
    float* cF1  = wsf + 2375680;        // 512
    float* cF2  = wsf + 2376192;        // 512
    float* FF1  = wsf + 2376704;        // 16392 (pad 16512)
    float* FF2R = wsf + 2393216;        // 16392 (pad 16512)
    float* S1   = wsf + 2409728;        // 8*2049*128 = 2,098,176
    float* S2R  = wsf + 4507904;        // 2,098,176

    hipLaunchKernelGGL(k1_h,        dim3(256),  dim3(256), 0, stream, x, Wm, bias, av, h, si, sj);
    hipLaunchKernelGGL(k2_rank,     dim3(128),  dim3(512), 0, stream, si, sj, perm, f1s, f2s, kk, e1, e2, own);
    hipLaunchKernelGGL(k3_chunksum, dim3(512),  dim3(256), 0, stream, h, perm, f1s, f2s, cS1, cS2, cF1, cF2);
    hipLaunchKernelGGL(k3_scan,     dim3(512),  dim3(256), 0, stream, h, perm, f1s, f2s, cS1, cS2, cF1, cF2, S1, S2R, FF1, FF2R);
    hipLaunchKernelGGL(k4_out,      dim3(2048), dim3(256), 0, stream, h, kk, e1, e2, own, S1, S2R, FF1, FF2R, out);
}